// Round 2
// baseline (23514.694 us; speedup 1.0000x reference)
//
#include <hip/hip_runtime.h>

#define NF   128
#define NH   4
#define FHD  32
#define BNEPS 1e-5f
#define SLOPE 0.2f

// ---------------- GEMM: XW = X @ W, X:[n,128], W:[128,128] ----------------
__global__ __launch_bounds__(256) void gemm_xw(
    const float* __restrict__ X, const float* __restrict__ W,
    float* __restrict__ XW, int nrows)
{
  __shared__ __align__(16) float sXT[128][68];  // 34816 B
  __shared__ __align__(16) float sW[32][128];   // 16384 B
  const int t = threadIdx.x;
  const int row0 = blockIdx.x * 64;

  for (int i = t; i < 64 * 32; i += 256) {
    int r = i >> 5, c4 = (i & 31) << 2;
    int gr = row0 + r;
    float4 v = make_float4(0.f, 0.f, 0.f, 0.f);
    if (gr < nrows) v = *(const float4*)&X[(size_t)gr * NF + c4];
    sXT[c4 + 0][r] = v.x; sXT[c4 + 1][r] = v.y;
    sXT[c4 + 2][r] = v.z; sXT[c4 + 3][r] = v.w;
  }

  const int tx = t & 15;
  const int ty = t >> 4;
  const int c0 = tx << 3;
  const int r0 = ty << 2;
  float acc[4][8];
  #pragma unroll
  for (int i = 0; i < 4; i++)
    #pragma unroll
    for (int j = 0; j < 8; j++) acc[i][j] = 0.f;

  for (int q = 0; q < 4; ++q) {
    __syncthreads();
    for (int i = t; i < 32 * 32; i += 256) {
      int kk = i >> 5, c4 = (i & 31) << 2;
      *(float4*)&sW[kk][c4] = *(const float4*)&W[(size_t)(q * 32 + kk) * NF + c4];
    }
    __syncthreads();
    #pragma unroll 4
    for (int kk = 0; kk < 32; ++kk) {
      int k = q * 32 + kk;
      float4 xv = *(const float4*)&sXT[k][r0];
      float4 w0 = *(const float4*)&sW[kk][c0];
      float4 w1 = *(const float4*)&sW[kk][c0 + 4];
      float xr[4] = {xv.x, xv.y, xv.z, xv.w};
      float wr[8] = {w0.x, w0.y, w0.z, w0.w, w1.x, w1.y, w1.z, w1.w};
      #pragma unroll
      for (int i = 0; i < 4; i++)
        #pragma unroll
        for (int j = 0; j < 8; j++)
          acc[i][j] = fmaf(xr[i], wr[j], acc[i][j]);
    }
  }

  #pragma unroll
  for (int i = 0; i < 4; i++) {
    int gr = row0 + r0 + i;
    if (gr < nrows) {
      *(float4*)&XW[(size_t)gr * NF + c0] =
          make_float4(acc[i][0], acc[i][1], acc[i][2], acc[i][3]);
      *(float4*)&XW[(size_t)gr * NF + c0 + 4] =
          make_float4(acc[i][4], acc[i][5], acc[i][6], acc[i][7]);
    }
  }
}

__global__ void al_kernel(const float* __restrict__ xw,
                          const float* __restrict__ a_src,
                          const float* __restrict__ a_dst,
                          float* __restrict__ al_s, float* __restrict__ al_d,
                          int nN)
{
  int t = blockIdx.x * blockDim.x + threadIdx.x;
  if (t >= nN * NH) return;
  int h = t & 3;
  const float4* xr = (const float4*)&xw[(size_t)t * FHD];
  const float4* as = (const float4*)&a_src[h * FHD];
  const float4* ad = (const float4*)&a_dst[h * FHD];
  float ss = 0.f, sd = 0.f;
  #pragma unroll
  for (int j = 0; j < 8; j++) {
    float4 v = xr[j], a = as[j], d = ad[j];
    ss += v.x * a.x + v.y * a.y + v.z * a.z + v.w * a.w;
    sd += v.x * d.x + v.y * d.y + v.z * d.z + v.w * d.w;
  }
  al_s[t] = ss;
  al_d[t] = sd;
}

__global__ void edge_kernel(const int* __restrict__ ei,
                            const float* __restrict__ xw,
                            const float* __restrict__ al_s,
                            const float* __restrict__ al_d,
                            float* __restrict__ num, float* __restrict__ den,
                            int nE, int nN)
{
  int t = blockIdx.x * blockDim.x + threadIdx.x;
  int total = (nE + nN) * NH;
  if (t >= total) return;
  int eid = t >> 2, h = t & 3;
  int src, dst;
  if (eid < nE) { src = ei[eid]; dst = ei[nE + eid]; }
  else          { src = dst = eid - nE; }
  float e = al_s[src * NH + h] + al_d[dst * NH + h];
  e = (e >= 0.f) ? e : SLOPE * e;
  float w = __expf(e);
  atomicAdd(&den[dst * NH + h], w);
  const float4* xr = (const float4*)&xw[((size_t)src * NH + h) * FHD];
  float* np_ = &num[((size_t)dst * NH + h) * FHD];
  #pragma unroll
  for (int j = 0; j < 8; ++j) {
    float4 v = xr[j];
    atomicAdd(np_ + j * 4 + 0, w * v.x);
    atomicAdd(np_ + j * 4 + 1, w * v.y);
    atomicAdd(np_ + j * 4 + 2, w * v.z);
    atomicAdd(np_ + j * 4 + 3, w * v.w);
  }
}

__global__ void finalize_stats(float* __restrict__ y_io,
                               const float* __restrict__ den,
                               const float* __restrict__ bias,
                               float* __restrict__ stats, int nN)
{
  int f = threadIdx.x;
  float b = bias[f];
  float s1 = 0.f, s2 = 0.f;
  for (int n = blockIdx.x; n < nN; n += gridDim.x) {
    float d = den[n * NH + (f >> 5)];
    float y = y_io[(size_t)n * NF + f] / d + b;
    y_io[(size_t)n * NF + f] = y;
    s1 += y;
    s2 += y * y;
  }
  atomicAdd(&stats[f], s1);
  atomicAdd(&stats[NF + f], s2);
}

__global__ void bn_elu(const float* __restrict__ y,
                       const float* __restrict__ stats,
                       const float* __restrict__ gamma,
                       const float* __restrict__ beta,
                       float* __restrict__ out, int nN)
{
  int t = blockIdx.x * blockDim.x + threadIdx.x;
  int total = nN * NF;
  if (t >= total) return;
  int f = t & (NF - 1);
  float inv_n = 1.f / (float)nN;
  float mu = stats[f] * inv_n;
  float var = stats[NF + f] * inv_n - mu * mu;
  float v = (y[t] - mu) * rsqrtf(var + BNEPS) * gamma[f] + beta[f];
  out[t] = (v > 0.f) ? v : expm1f(v);
}

extern "C" void kernel_launch(void* const* d_in, const int* in_sizes, int n_in,
                              void* d_out, int out_size, void* d_ws, size_t ws_size,
                              hipStream_t stream)
{
  const float* x   = (const float*)d_in[0];
  const int*   ei  = (const int*)d_in[1];
  const float* W1  = (const float*)d_in[2];
  const float* a1s = (const float*)d_in[3];
  const float* a1d = (const float*)d_in[4];
  const float* b1  = (const float*)d_in[5];
  const float* g1  = (const float*)d_in[6];
  const float* be1 = (const float*)d_in[7];
  const float* W2  = (const float*)d_in[8];
  const float* a2s = (const float*)d_in[9];
  const float* a2d = (const float*)d_in[10];
  const float* b2  = (const float*)d_in[11];
  const float* g2  = (const float*)d_in[12];
  const float* be2 = (const float*)d_in[13];
  float* out = (float*)d_out;

  const int nN = in_sizes[0] / NF;
  const int nE = in_sizes[1] / 2;

  float* ws = (float*)d_ws;
  size_t off = 0;
  float* xw    = ws + off; off += (size_t)nN * NF;
  float* num   = ws + off; off += (size_t)nN * NF;   // zero-region start
  float* den   = ws + off; off += (size_t)nN * NH;
  float* stats = ws + off; off += 256;               // zero-region end
  float* ALs   = ws + off; off += (size_t)nN * NH;
  float* ALd   = ws + off; off += (size_t)nN * NH;
  float* hbuf  = out;                                // layer-1 output in d_out

  size_t zero_bytes = ((size_t)nN * NF + (size_t)nN * NH + 256) * sizeof(float);

  const int gemm_grid = (nN + 63) / 64;
  const int al_grid   = (nN * NH + 255) / 256;
  const int edge_grid = (int)(((long long)(nE + nN) * NH + 255) / 256);
  const int bn_grid   = (nN * NF + 255) / 256;

  // ---------------- layer 1 ----------------
  hipMemsetAsync(num, 0, zero_bytes, stream);
  gemm_xw<<<gemm_grid, 256, 0, stream>>>(x, W1, xw, nN);
  al_kernel<<<al_grid, 256, 0, stream>>>(xw, a1s, a1d, ALs, ALd, nN);
  edge_kernel<<<edge_grid, 256, 0, stream>>>(ei, xw, ALs, ALd, num, den, nE, nN);
  finalize_stats<<<2048, 128, 0, stream>>>(num, den, b1, stats, nN);
  bn_elu<<<bn_grid, 256, 0, stream>>>(num, stats, g1, be1, hbuf, nN);

  // ---------------- layer 2 ----------------
  hipMemsetAsync(num, 0, zero_bytes, stream);
  gemm_xw<<<gemm_grid, 256, 0, stream>>>(hbuf, W2, xw, nN);
  al_kernel<<<al_grid, 256, 0, stream>>>(xw, a2s, a2d, ALs, ALd, nN);
  edge_kernel<<<edge_grid, 256, 0, stream>>>(ei, xw, ALs, ALd, num, den, nE, nN);
  finalize_stats<<<2048, 128, 0, stream>>>(num, den, b2, stats, nN);
  bn_elu<<<bn_grid, 256, 0, stream>>>(num, stats, g2, be2, out, nN);
}

// Round 8
// 905.097 us; speedup vs baseline: 25.9803x; 25.9803x over previous
//
#include <hip/hip_runtime.h>

#define NF   128
#define NH   4
#define FHD  32
#define BNEPS 1e-5f
#define SLOPE 0.2f

// ---------------- GEMM: XW = X @ W, X:[n,128], W:[128,128] ----------------
__global__ __launch_bounds__(256) void gemm_xw(
    const float* __restrict__ X, const float* __restrict__ W,
    float* __restrict__ XW, int nrows)
{
  __shared__ __align__(16) float sXT[128][68];
  __shared__ __align__(16) float sW[32][128];
  const int t = threadIdx.x;
  const int row0 = blockIdx.x * 64;

  for (int i = t; i < 64 * 32; i += 256) {
    int r = i >> 5, c4 = (i & 31) << 2;
    int gr = row0 + r;
    float4 v = make_float4(0.f, 0.f, 0.f, 0.f);
    if (gr < nrows) v = *(const float4*)&X[(size_t)gr * NF + c4];
    sXT[c4 + 0][r] = v.x; sXT[c4 + 1][r] = v.y;
    sXT[c4 + 2][r] = v.z; sXT[c4 + 3][r] = v.w;
  }

  const int tx = t & 15;
  const int ty = t >> 4;
  const int c0 = tx << 3;
  const int r0 = ty << 2;
  float acc[4][8];
  #pragma unroll
  for (int i = 0; i < 4; i++)
    #pragma unroll
    for (int j = 0; j < 8; j++) acc[i][j] = 0.f;

  for (int q = 0; q < 4; ++q) {
    __syncthreads();
    for (int i = t; i < 32 * 32; i += 256) {
      int kk = i >> 5, c4 = (i & 31) << 2;
      *(float4*)&sW[kk][c4] = *(const float4*)&W[(size_t)(q * 32 + kk) * NF + c4];
    }
    __syncthreads();
    #pragma unroll 4
    for (int kk = 0; kk < 32; ++kk) {
      int k = q * 32 + kk;
      float4 xv = *(const float4*)&sXT[k][r0];
      float4 w0 = *(const float4*)&sW[kk][c0];
      float4 w1 = *(const float4*)&sW[kk][c0 + 4];
      float xr[4] = {xv.x, xv.y, xv.z, xv.w};
      float wr[8] = {w0.x, w0.y, w0.z, w0.w, w1.x, w1.y, w1.z, w1.w};
      #pragma unroll
      for (int i = 0; i < 4; i++)
        #pragma unroll
        for (int j = 0; j < 8; j++)
          acc[i][j] = fmaf(xr[i], wr[j], acc[i][j]);
    }
  }

  #pragma unroll
  for (int i = 0; i < 4; i++) {
    int gr = row0 + r0 + i;
    if (gr < nrows) {
      *(float4*)&XW[(size_t)gr * NF + c0] =
          make_float4(acc[i][0], acc[i][1], acc[i][2], acc[i][3]);
      *(float4*)&XW[(size_t)gr * NF + c0 + 4] =
          make_float4(acc[i][4], acc[i][5], acc[i][6], acc[i][7]);
    }
  }
}

// ---------------- attention logits ----------------
__global__ void al_kernel(const float* __restrict__ xw,
                          const float* __restrict__ a_src,
                          const float* __restrict__ a_dst,
                          float* __restrict__ al_s, float* __restrict__ al_d,
                          int nN)
{
  int t = blockIdx.x * blockDim.x + threadIdx.x;
  if (t >= nN * NH) return;
  int h = t & 3;
  const float4* xr = (const float4*)&xw[(size_t)t * FHD];
  const float4* as = (const float4*)&a_src[h * FHD];
  const float4* ad = (const float4*)&a_dst[h * FHD];
  float ss = 0.f, sd = 0.f;
  #pragma unroll
  for (int j = 0; j < 8; j++) {
    float4 v = xr[j], a = as[j], d = ad[j];
    ss += v.x * a.x + v.y * a.y + v.z * a.z + v.w * a.w;
    sd += v.x * d.x + v.y * d.y + v.z * d.z + v.w * d.w;
  }
  al_s[t] = ss;
  al_d[t] = sd;
}

// ---------------- CSR build ----------------
__global__ void count_kernel(const int* __restrict__ ei, int* __restrict__ cnt,
                             int nE)
{
  int e = blockIdx.x * blockDim.x + threadIdx.x;
  if (e < nE) atomicAdd(&cnt[ei[nE + e]], 1);
}

__global__ void scan1(const int* __restrict__ cnt, int* __restrict__ excl,
                      int* __restrict__ blockSums, int n)
{
  __shared__ int s[256];
  int i = blockIdx.x * 256 + threadIdx.x;
  int v = (i < n) ? cnt[i] : 0;
  s[threadIdx.x] = v;
  __syncthreads();
  for (int ofs = 1; ofs < 256; ofs <<= 1) {
    int t = (threadIdx.x >= ofs) ? s[threadIdx.x - ofs] : 0;
    __syncthreads();
    s[threadIdx.x] += t;
    __syncthreads();
  }
  if (i < n) excl[i] = s[threadIdx.x] - v;
  if (threadIdx.x == 255) blockSums[blockIdx.x] = s[255];
}

__global__ void scan2(int* __restrict__ blockSums, int nb)
{
  __shared__ int s[1024];
  int tid = threadIdx.x;
  int v = (tid < nb) ? blockSums[tid] : 0;
  s[tid] = v;
  __syncthreads();
  for (int ofs = 1; ofs < 1024; ofs <<= 1) {
    int t = (tid >= ofs) ? s[tid - ofs] : 0;
    __syncthreads();
    s[tid] += t;
    __syncthreads();
  }
  if (tid < nb) blockSums[tid] = s[tid] - v;   // exclusive
}

__global__ void scan3(const int* __restrict__ excl,
                      const int* __restrict__ blockSums,
                      int* __restrict__ rowptr, int* __restrict__ cursor,
                      int n, int nE)
{
  int i = blockIdx.x * blockDim.x + threadIdx.x;
  if (i < n) {
    int v = excl[i] + blockSums[i >> 8];
    rowptr[i] = v;
    cursor[i] = v;
  }
  if (i == n) rowptr[n] = nE;
}

__global__ void scatter_kernel(const int* __restrict__ ei,
                               int* __restrict__ cursor,
                               int* __restrict__ adj, int nE)
{
  int e = blockIdx.x * blockDim.x + threadIdx.x;
  if (e >= nE) return;
  int src = ei[e];
  int dst = ei[nE + e];
  int pos = atomicAdd(&cursor[dst], 1);
  adj[pos] = src;
}

// ---------------- gather: one wave per node -------------------------------
__global__ __launch_bounds__(256) void gat_gather(
    const int* __restrict__ rowptr, const int* __restrict__ adj,
    const float* __restrict__ xw,
    const float* __restrict__ ALs, const float* __restrict__ ALd,
    const float* __restrict__ bias,
    float* __restrict__ y, int nN)
{
  int wid = (blockIdx.x * blockDim.x + threadIdx.x) >> 6;
  if (wid >= nN) return;
  int node = __builtin_amdgcn_readfirstlane(wid);
  int lane = threadIdx.x & 63;
  int h = lane >> 4;                 // head of features 2*lane, 2*lane+1
  float ad = ALd[node * NH + h];

  float acc0, acc1, den;
  {  // self loop
    float e = ALs[node * NH + h] + ad;
    e = (e >= 0.f) ? e : SLOPE * e;
    float w = __expf(e);
    float2 v = *(const float2*)&xw[(size_t)node * NF + lane * 2];
    acc0 = w * v.x; acc1 = w * v.y; den = w;
  }

  int beg = rowptr[node];
  int end = rowptr[node + 1];
  for (int p = beg; p < end; ++p) {
    int src = adj[p];
    float e = ALs[src * NH + h] + ad;
    e = (e >= 0.f) ? e : SLOPE * e;
    float w = __expf(e);
    float2 v = *(const float2*)&xw[(size_t)src * NF + lane * 2];
    acc0 = fmaf(w, v.x, acc0);
    acc1 = fmaf(w, v.y, acc1);
    den += w;
  }

  float inv = 1.f / den;
  float2 o;
  o.x = acc0 * inv + bias[lane * 2];
  o.y = acc1 * inv + bias[lane * 2 + 1];
  *(float2*)&y[(size_t)node * NF + lane * 2] = o;
}

// ---------------- BN stats + BN/ELU ----------------------------------------
__global__ void stats_kernel(const float* __restrict__ y,
                             float* __restrict__ stats, int nN)
{
  int f = threadIdx.x;  // 128
  float s1 = 0.f, s2 = 0.f;
  for (int n = blockIdx.x; n < nN; n += gridDim.x) {
    float v = y[(size_t)n * NF + f];
    s1 += v;
    s2 += v * v;
  }
  atomicAdd(&stats[f], s1);
  atomicAdd(&stats[NF + f], s2);
}

__global__ void bn_elu(const float* __restrict__ y,
                       const float* __restrict__ stats,
                       const float* __restrict__ gamma,
                       const float* __restrict__ beta,
                       float* __restrict__ out, int nN)
{
  int t = blockIdx.x * blockDim.x + threadIdx.x;
  int total = nN * NF;
  if (t >= total) return;
  int f = t & (NF - 1);
  float inv_n = 1.f / (float)nN;
  float mu = stats[f] * inv_n;
  float var = stats[NF + f] * inv_n - mu * mu;
  float v = (y[t] - mu) * rsqrtf(var + BNEPS) * gamma[f] + beta[f];
  out[t] = (v > 0.f) ? v : expm1f(v);
}

extern "C" void kernel_launch(void* const* d_in, const int* in_sizes, int n_in,
                              void* d_out, int out_size, void* d_ws, size_t ws_size,
                              hipStream_t stream)
{
  const float* x   = (const float*)d_in[0];
  const int*   ei  = (const int*)d_in[1];
  const float* W1  = (const float*)d_in[2];
  const float* a1s = (const float*)d_in[3];
  const float* a1d = (const float*)d_in[4];
  const float* b1  = (const float*)d_in[5];
  const float* g1  = (const float*)d_in[6];
  const float* be1 = (const float*)d_in[7];
  const float* W2  = (const float*)d_in[8];
  const float* a2s = (const float*)d_in[9];
  const float* a2d = (const float*)d_in[10];
  const float* b2  = (const float*)d_in[11];
  const float* g2  = (const float*)d_in[12];
  const float* be2 = (const float*)d_in[13];
  float* out = (float*)d_out;

  const int nN = in_sizes[0] / NF;   // 100000
  const int nE = in_sizes[1] / 2;    // 1600000
  const int nb = (nN + 255) / 256;   // scan blocks (<=1024 required)

  float* ws = (float*)d_ws;
  size_t off = 0;
  float* xw    = ws + off; off += (size_t)nN * NF;
  float* ybuf  = ws + off; off += (size_t)nN * NF;
  float* ALs   = ws + off; off += (size_t)nN * NH;
  float* ALd   = ws + off; off += (size_t)nN * NH;
  float* stats = ws + off; off += 256;
  int* ibase   = (int*)(ws + off);
  int* cnt       = ibase;                 // nN
  int* excl      = ibase + nN;            // nN
  int* blockSums = ibase + 2 * nN;        // nb (<1024)
  int* rowptr    = ibase + 2 * nN + 1024; // nN+1
  int* cursor    = rowptr + nN + 1;       // nN
  int* adj       = cursor + nN;           // nE
  float* hbuf  = out;                     // layer-1 activations live in d_out

  const int gemm_grid = (nN + 63) / 64;
  const int al_grid   = (nN * NH + 255) / 256;
  const int e_grid    = (nE + 255) / 256;
  const int g_grid    = (nN * 64 + 255) / 256;   // one wave per node
  const int bn_grid   = (nN * NF + 255) / 256;

  // ---------------- CSR build (once, shared by both layers) ----------------
  hipMemsetAsync(cnt, 0, (size_t)nN * sizeof(int), stream);
  count_kernel<<<e_grid, 256, 0, stream>>>(ei, cnt, nE);
  scan1<<<nb, 256, 0, stream>>>(cnt, excl, blockSums, nN);
  scan2<<<1, 1024, 0, stream>>>(blockSums, nb);
  scan3<<<(nN + 256) / 256, 256, 0, stream>>>(excl, blockSums, rowptr, cursor, nN, nE);
  scatter_kernel<<<e_grid, 256, 0, stream>>>(ei, cursor, adj, nE);

  // ---------------- layer 1 ----------------
  hipMemsetAsync(stats, 0, 256 * sizeof(float), stream);
  gemm_xw<<<gemm_grid, 256, 0, stream>>>(x, W1, xw, nN);
  al_kernel<<<al_grid, 256, 0, stream>>>(xw, a1s, a1d, ALs, ALd, nN);
  gat_gather<<<g_grid, 256, 0, stream>>>(rowptr, adj, xw, ALs, ALd, b1, ybuf, nN);
  stats_kernel<<<1024, 128, 0, stream>>>(ybuf, stats, nN);
  bn_elu<<<bn_grid, 256, 0, stream>>>(ybuf, stats, g1, be1, hbuf, nN);

  // ---------------- layer 2 ----------------
  hipMemsetAsync(stats, 0, 256 * sizeof(float), stream);
  gemm_xw<<<gemm_grid, 256, 0, stream>>>(hbuf, W2, xw, nN);
  al_kernel<<<al_grid, 256, 0, stream>>>(xw, a2s, a2d, ALs, ALd, nN);
  gat_gather<<<g_grid, 256, 0, stream>>>(rowptr, adj, xw, ALs, ALd, b2, ybuf, nN);
  stats_kernel<<<1024, 128, 0, stream>>>(ybuf, stats, nN);
  bn_elu<<<bn_grid, 256, 0, stream>>>(ybuf, stats, g2, be2, out, nN);
}

// Round 10
// 783.517 us; speedup vs baseline: 30.0117x; 1.1552x over previous
//
#include <hip/hip_runtime.h>

#define NF   128
#define NH   4
#define FHD  32
#define BNEPS 1e-5f
#define SLOPE 0.2f

typedef unsigned int uint32;

// bf16 helpers (packed 2×bf16 in a uint32; elem0 = bits[15:0], elem1 = bits[31:16])
__device__ __forceinline__ float bf_lo(uint32 u) { return __uint_as_float(u << 16); }
__device__ __forceinline__ float bf_hi(uint32 u) { return __uint_as_float(u & 0xFFFF0000u); }
__device__ __forceinline__ uint32 bf_rnd(float x) {          // RNE round to bf16
  uint32 u = __float_as_uint(x);
  return (u + 0x7FFFu + ((u >> 16) & 1u)) >> 16;
}
__device__ __forceinline__ uint32 pack2(float a, float b) {
  return bf_rnd(a) | (bf_rnd(b) << 16);
}

// ------- GEMM: XWB = bf16(X @ W), X:[n,128] fp32, W:[128,128] fp32 ---------
__global__ __launch_bounds__(256) void gemm_xw_bf(
    const float* __restrict__ X, const float* __restrict__ W,
    uint32* __restrict__ XWB, int nrows)
{
  __shared__ __align__(16) float sXT[128][68];
  __shared__ __align__(16) float sW[32][128];
  const int t = threadIdx.x;
  const int row0 = blockIdx.x * 64;

  for (int i = t; i < 64 * 32; i += 256) {
    int r = i >> 5, c4 = (i & 31) << 2;
    int gr = row0 + r;
    float4 v = make_float4(0.f, 0.f, 0.f, 0.f);
    if (gr < nrows) v = *(const float4*)&X[(size_t)gr * NF + c4];
    sXT[c4 + 0][r] = v.x; sXT[c4 + 1][r] = v.y;
    sXT[c4 + 2][r] = v.z; sXT[c4 + 3][r] = v.w;
  }

  const int tx = t & 15;
  const int ty = t >> 4;
  const int c0 = tx << 3;
  const int r0 = ty << 2;
  float acc[4][8];
  #pragma unroll
  for (int i = 0; i < 4; i++)
    #pragma unroll
    for (int j = 0; j < 8; j++) acc[i][j] = 0.f;

  for (int q = 0; q < 4; ++q) {
    __syncthreads();
    for (int i = t; i < 32 * 32; i += 256) {
      int kk = i >> 5, c4 = (i & 31) << 2;
      *(float4*)&sW[kk][c4] = *(const float4*)&W[(size_t)(q * 32 + kk) * NF + c4];
    }
    __syncthreads();
    #pragma unroll 4
    for (int kk = 0; kk < 32; ++kk) {
      int k = q * 32 + kk;
      float4 xv = *(const float4*)&sXT[k][r0];
      float4 w0 = *(const float4*)&sW[kk][c0];
      float4 w1 = *(const float4*)&sW[kk][c0 + 4];
      float xr[4] = {xv.x, xv.y, xv.z, xv.w};
      float wr[8] = {w0.x, w0.y, w0.z, w0.w, w1.x, w1.y, w1.z, w1.w};
      #pragma unroll
      for (int i = 0; i < 4; i++)
        #pragma unroll
        for (int j = 0; j < 8; j++)
          acc[i][j] = fmaf(xr[i], wr[j], acc[i][j]);
    }
  }

  #pragma unroll
  for (int i = 0; i < 4; i++) {
    int gr = row0 + r0 + i;
    if (gr < nrows) {
      uint4 pk;
      pk.x = pack2(acc[i][0], acc[i][1]);
      pk.y = pack2(acc[i][2], acc[i][3]);
      pk.z = pack2(acc[i][4], acc[i][5]);
      pk.w = pack2(acc[i][6], acc[i][7]);
      *(uint4*)&XWB[(size_t)gr * 64 + (c0 >> 1)] = pk;
    }
  }
}

// ------- attention logits from bf16 xw -------------------------------------
__global__ void al_kernel_bf(const uint32* __restrict__ xwb,
                             const float* __restrict__ a_src,
                             const float* __restrict__ a_dst,
                             float* __restrict__ al_s, float* __restrict__ al_d,
                             int nN)
{
  int t = blockIdx.x * blockDim.x + threadIdx.x;
  if (t >= nN * NH) return;
  int h = t & 3;
  const uint32* xr = &xwb[(size_t)t * 16];
  const float* as = &a_src[h * FHD];
  const float* ad = &a_dst[h * FHD];
  float ss = 0.f, sd = 0.f;
  #pragma unroll
  for (int j = 0; j < 16; j++) {
    uint32 u = xr[j];
    float f0 = bf_lo(u), f1 = bf_hi(u);
    ss += f0 * as[2 * j] + f1 * as[2 * j + 1];
    sd += f0 * ad[2 * j] + f1 * ad[2 * j + 1];
  }
  al_s[t] = ss;
  al_d[t] = sd;
}

// ---------------- CSR build ----------------
__global__ void count_kernel(const int* __restrict__ ei, int* __restrict__ cnt,
                             int nE)
{
  int e = blockIdx.x * blockDim.x + threadIdx.x;
  if (e < nE) atomicAdd(&cnt[ei[nE + e]], 1);
}

__global__ void scan1(const int* __restrict__ cnt, int* __restrict__ excl,
                      int* __restrict__ blockSums, int n)
{
  __shared__ int s[256];
  int i = blockIdx.x * 256 + threadIdx.x;
  int v = (i < n) ? cnt[i] : 0;
  s[threadIdx.x] = v;
  __syncthreads();
  for (int ofs = 1; ofs < 256; ofs <<= 1) {
    int t = (threadIdx.x >= ofs) ? s[threadIdx.x - ofs] : 0;
    __syncthreads();
    s[threadIdx.x] += t;
    __syncthreads();
  }
  if (i < n) excl[i] = s[threadIdx.x] - v;
  if (threadIdx.x == 255) blockSums[blockIdx.x] = s[255];
}

__global__ void scan2(int* __restrict__ blockSums, int nb)
{
  __shared__ int s[1024];
  int tid = threadIdx.x;
  int v = (tid < nb) ? blockSums[tid] : 0;
  s[tid] = v;
  __syncthreads();
  for (int ofs = 1; ofs < 1024; ofs <<= 1) {
    int t = (tid >= ofs) ? s[tid - ofs] : 0;
    __syncthreads();
    s[tid] += t;
    __syncthreads();
  }
  if (tid < nb) blockSums[tid] = s[tid] - v;   // exclusive
}

__global__ void scan3(const int* __restrict__ excl,
                      const int* __restrict__ blockSums,
                      int* __restrict__ rowptr, int* __restrict__ cursor,
                      int n, int nE)
{
  int i = blockIdx.x * blockDim.x + threadIdx.x;
  if (i < n) {
    int v = excl[i] + blockSums[i >> 8];
    rowptr[i] = v;
    cursor[i] = v;
  }
  if (i == n) rowptr[n] = nE;
}

__global__ void scatter_kernel(const int* __restrict__ ei,
                               int* __restrict__ cursor,
                               int* __restrict__ adj, int nE)
{
  int e = blockIdx.x * blockDim.x + threadIdx.x;
  if (e >= nE) return;
  int src = ei[e];
  int dst = ei[nE + e];
  int pos = atomicAdd(&cursor[dst], 1);
  adj[pos] = src;
}

// ------- gather: one wave per node, bf16 rows (256B/edge) ------------------
__global__ __launch_bounds__(256) void gat_gather_bf(
    const int* __restrict__ rowptr, const int* __restrict__ adj,
    const uint32* __restrict__ xwb,
    const float* __restrict__ ALs, const float* __restrict__ ALd,
    const float* __restrict__ bias,
    float* __restrict__ y, int nN)
{
  int wid = (blockIdx.x * blockDim.x + threadIdx.x) >> 6;
  if (wid >= nN) return;
  int node = __builtin_amdgcn_readfirstlane(wid);
  int lane = threadIdx.x & 63;
  int h = lane >> 4;                 // head of features 2*lane, 2*lane+1
  float ad = ALd[node * NH + h];

  float acc0, acc1, den;
  {  // self loop
    float e = ALs[node * NH + h] + ad;
    e = (e >= 0.f) ? e : SLOPE * e;
    float w = __expf(e);
    uint32 u = xwb[(size_t)node * 64 + lane];
    acc0 = w * bf_lo(u); acc1 = w * bf_hi(u); den = w;
  }

  int beg = rowptr[node];
  int end = rowptr[node + 1];
  int p = beg;
  for (; p + 1 < end; p += 2) {       // 2 independent row loads in flight
    int s0 = adj[p], s1 = adj[p + 1];
    uint32 u0 = xwb[(size_t)s0 * 64 + lane];
    uint32 u1 = xwb[(size_t)s1 * 64 + lane];
    float e0 = ALs[s0 * NH + h] + ad; e0 = (e0 >= 0.f) ? e0 : SLOPE * e0;
    float e1 = ALs[s1 * NH + h] + ad; e1 = (e1 >= 0.f) ? e1 : SLOPE * e1;
    float w0 = __expf(e0), w1 = __expf(e1);
    acc0 = fmaf(w0, bf_lo(u0), acc0); acc1 = fmaf(w0, bf_hi(u0), acc1); den += w0;
    acc0 = fmaf(w1, bf_lo(u1), acc0); acc1 = fmaf(w1, bf_hi(u1), acc1); den += w1;
  }
  if (p < end) {
    int s0 = adj[p];
    uint32 u0 = xwb[(size_t)s0 * 64 + lane];
    float e0 = ALs[s0 * NH + h] + ad; e0 = (e0 >= 0.f) ? e0 : SLOPE * e0;
    float w0 = __expf(e0);
    acc0 = fmaf(w0, bf_lo(u0), acc0); acc1 = fmaf(w0, bf_hi(u0), acc1); den += w0;
  }

  float inv = 1.f / den;
  float2 o;
  o.x = acc0 * inv + bias[lane * 2];
  o.y = acc1 * inv + bias[lane * 2 + 1];
  *(float2*)&y[(size_t)node * NF + lane * 2] = o;
}

// ---------------- BN stats + BN/ELU ----------------------------------------
__global__ void stats_kernel(const float* __restrict__ y,
                             float* __restrict__ stats, int nN)
{
  int f = threadIdx.x;  // 128
  float s1 = 0.f, s2 = 0.f;
  for (int n = blockIdx.x; n < nN; n += gridDim.x) {
    float v = y[(size_t)n * NF + f];
    s1 += v;
    s2 += v * v;
  }
  atomicAdd(&stats[f], s1);
  atomicAdd(&stats[NF + f], s2);
}

__global__ void bn_elu(const float* __restrict__ y,
                       const float* __restrict__ stats,
                       const float* __restrict__ gamma,
                       const float* __restrict__ beta,
                       float* __restrict__ out, int nN)
{
  int t = blockIdx.x * blockDim.x + threadIdx.x;
  int total = nN * NF;
  if (t >= total) return;
  int f = t & (NF - 1);
  float inv_n = 1.f / (float)nN;
  float mu = stats[f] * inv_n;
  float var = stats[NF + f] * inv_n - mu * mu;
  float v = (y[t] - mu) * rsqrtf(var + BNEPS) * gamma[f] + beta[f];
  out[t] = (v > 0.f) ? v : expm1f(v);
}

extern "C" void kernel_launch(void* const* d_in, const int* in_sizes, int n_in,
                              void* d_out, int out_size, void* d_ws, size_t ws_size,
                              hipStream_t stream)
{
  const float* x   = (const float*)d_in[0];
  const int*   ei  = (const int*)d_in[1];
  const float* W1  = (const float*)d_in[2];
  const float* a1s = (const float*)d_in[3];
  const float* a1d = (const float*)d_in[4];
  const float* b1  = (const float*)d_in[5];
  const float* g1  = (const float*)d_in[6];
  const float* be1 = (const float*)d_in[7];
  const float* W2  = (const float*)d_in[8];
  const float* a2s = (const float*)d_in[9];
  const float* a2d = (const float*)d_in[10];
  const float* b2  = (const float*)d_in[11];
  const float* g2  = (const float*)d_in[12];
  const float* be2 = (const float*)d_in[13];
  float* out = (float*)d_out;

  const int nN = in_sizes[0] / NF;   // 100000
  const int nE = in_sizes[1] / 2;    // 1600000
  const int nb = (nN + 255) / 256;   // scan blocks (<=1024 required)

  float* ws = (float*)d_ws;
  size_t off = 0;
  uint32* xwb  = (uint32*)(ws + off); off += (size_t)nN * 64;   // bf16 xw, 25.6 MB
  float* ybuf  = ws + off; off += (size_t)nN * NF;
  float* ALs   = ws + off; off += (size_t)nN * NH;
  float* ALd   = ws + off; off += (size_t)nN * NH;
  float* stats = ws + off; off += 256;
  int* ibase   = (int*)(ws + off);
  int* cnt       = ibase;                 // nN
  int* excl      = ibase + nN;            // nN
  int* blockSums = ibase + 2 * nN;        // nb (<1024)
  int* rowptr    = ibase + 2 * nN + 1024; // nN+1
  int* cursor    = rowptr + nN + 1;       // nN
  int* adj       = cursor + nN;           // nE
  float* hbuf  = out;                     // layer-1 activations live in d_out

  const int gemm_grid = (nN + 63) / 64;
  const int al_grid   = (nN * NH + 255) / 256;
  const int e_grid    = (nE + 255) / 256;
  const int g_grid    = (nN * 64 + 255) / 256;   // one wave per node
  const int bn_grid   = (nN * NF + 255) / 256;

  // ---------------- CSR build (once, shared by both layers) ----------------
  hipMemsetAsync(cnt, 0, (size_t)nN * sizeof(int), stream);
  count_kernel<<<e_grid, 256, 0, stream>>>(ei, cnt, nE);
  scan1<<<nb, 256, 0, stream>>>(cnt, excl, blockSums, nN);
  scan2<<<1, 1024, 0, stream>>>(blockSums, nb);
  scan3<<<(nN + 256) / 256, 256, 0, stream>>>(excl, blockSums, rowptr, cursor, nN, nE);
  scatter_kernel<<<e_grid, 256, 0, stream>>>(ei, cursor, adj, nE);

  // ---------------- layer 1 ----------------
  hipMemsetAsync(stats, 0, 256 * sizeof(float), stream);
  gemm_xw_bf<<<gemm_grid, 256, 0, stream>>>(x, W1, xwb, nN);
  al_kernel_bf<<<al_grid, 256, 0, stream>>>(xwb, a1s, a1d, ALs, ALd, nN);
  gat_gather_bf<<<g_grid, 256, 0, stream>>>(rowptr, adj, xwb, ALs, ALd, b1, ybuf, nN);
  stats_kernel<<<1024, 128, 0, stream>>>(ybuf, stats, nN);
  bn_elu<<<bn_grid, 256, 0, stream>>>(ybuf, stats, g1, be1, hbuf, nN);

  // ---------------- layer 2 ----------------
  hipMemsetAsync(stats, 0, 256 * sizeof(float), stream);
  gemm_xw_bf<<<gemm_grid, 256, 0, stream>>>(hbuf, W2, xwb, nN);
  al_kernel_bf<<<al_grid, 256, 0, stream>>>(xwb, a2s, a2d, ALs, ALd, nN);
  gat_gather_bf<<<g_grid, 256, 0, stream>>>(rowptr, adj, xwb, ALs, ALd, b2, ybuf, nN);
  stats_kernel<<<1024, 128, 0, stream>>>(ybuf, stats, nN);
  bn_elu<<<bn_grid, 256, 0, stream>>>(ybuf, stats, g2, be2, out, nN);
}

// Round 12
// 635.071 us; speedup vs baseline: 37.0269x; 1.2337x over previous
//
#include <hip/hip_runtime.h>

#define NF   128
#define NH   4
#define FHD  32
#define BNEPS 1e-5f
#define SLOPE 0.2f

typedef unsigned int uint32;

// bf16 helpers (packed 2×bf16 in a uint32; elem0 = bits[15:0], elem1 = bits[31:16])
__device__ __forceinline__ float bf_lo(uint32 u) { return __uint_as_float(u << 16); }
__device__ __forceinline__ float bf_hi(uint32 u) { return __uint_as_float(u & 0xFFFF0000u); }
__device__ __forceinline__ uint32 bf_rnd(float x) {          // RNE round to bf16
  uint32 u = __float_as_uint(x);
  return (u + 0x7FFFu + ((u >> 16) & 1u)) >> 16;
}
__device__ __forceinline__ uint32 pack2(float a, float b) {
  return bf_rnd(a) | (bf_rnd(b) << 16);
}

// ------- GEMM + fused attention logits -------------------------------------
// XWB = bf16(X @ W); ALs/ALd = per-(node,head) logit dots from fp32 acc.
__global__ __launch_bounds__(256) void gemm_xw_al(
    const float* __restrict__ X, const float* __restrict__ W,
    const float* __restrict__ a_src, const float* __restrict__ a_dst,
    uint32* __restrict__ XWB, float* __restrict__ ALs, float* __restrict__ ALd,
    int nrows)
{
  __shared__ __align__(16) float sXT[128][68];
  __shared__ __align__(16) float sW[32][128];
  __shared__ float sAs[128], sAd[128];
  const int t = threadIdx.x;
  const int row0 = blockIdx.x * 64;

  for (int i = t; i < 64 * 32; i += 256) {
    int r = i >> 5, c4 = (i & 31) << 2;
    int gr = row0 + r;
    float4 v = make_float4(0.f, 0.f, 0.f, 0.f);
    if (gr < nrows) v = *(const float4*)&X[(size_t)gr * NF + c4];
    sXT[c4 + 0][r] = v.x; sXT[c4 + 1][r] = v.y;
    sXT[c4 + 2][r] = v.z; sXT[c4 + 3][r] = v.w;
  }
  if (t < 128) sAs[t] = a_src[t];
  else         sAd[t - 128] = a_dst[t - 128];

  const int tx = t & 15;
  const int ty = t >> 4;
  const int c0 = tx << 3;
  const int r0 = ty << 2;
  float acc[4][8];
  #pragma unroll
  for (int i = 0; i < 4; i++)
    #pragma unroll
    for (int j = 0; j < 8; j++) acc[i][j] = 0.f;

  for (int q = 0; q < 4; ++q) {
    __syncthreads();
    for (int i = t; i < 32 * 32; i += 256) {
      int kk = i >> 5, c4 = (i & 31) << 2;
      *(float4*)&sW[kk][c4] = *(const float4*)&W[(size_t)(q * 32 + kk) * NF + c4];
    }
    __syncthreads();
    #pragma unroll 4
    for (int kk = 0; kk < 32; ++kk) {
      int k = q * 32 + kk;
      float4 xv = *(const float4*)&sXT[k][r0];
      float4 w0 = *(const float4*)&sW[kk][c0];
      float4 w1 = *(const float4*)&sW[kk][c0 + 4];
      float xr[4] = {xv.x, xv.y, xv.z, xv.w};
      float wr[8] = {w0.x, w0.y, w0.z, w0.w, w1.x, w1.y, w1.z, w1.w};
      #pragma unroll
      for (int i = 0; i < 4; i++)
        #pragma unroll
        for (int j = 0; j < 8; j++)
          acc[i][j] = fmaf(xr[i], wr[j], acc[i][j]);
    }
  }

  const int hd  = tx >> 2;          // head of this thread's 8 cols
  const int off = (tx & 3) << 3;    // offset within head
  #pragma unroll
  for (int i = 0; i < 4; i++) {
    int gr = row0 + r0 + i;
    float ps = 0.f, pd = 0.f;
    #pragma unroll
    for (int j = 0; j < 8; j++) {
      ps += acc[i][j] * sAs[hd * FHD + off + j];
      pd += acc[i][j] * sAd[hd * FHD + off + j];
    }
    // quad reduce (threads t, t^1, t^2, t^3 share row-group & head)
    ps += __shfl_xor(ps, 1); ps += __shfl_xor(ps, 2);
    pd += __shfl_xor(pd, 1); pd += __shfl_xor(pd, 2);
    if (gr < nrows) {
      uint4 pk;
      pk.x = pack2(acc[i][0], acc[i][1]);
      pk.y = pack2(acc[i][2], acc[i][3]);
      pk.z = pack2(acc[i][4], acc[i][5]);
      pk.w = pack2(acc[i][6], acc[i][7]);
      *(uint4*)&XWB[(size_t)gr * 64 + (c0 >> 1)] = pk;
      if ((t & 3) == 0) {
        ALs[gr * NH + hd] = ps;
        ALd[gr * NH + hd] = pd;
      }
    }
  }
}

// ---------------- CSR build (rank-based, no atomic in scatter) -------------
__global__ void count_rank_kernel(const int* __restrict__ ei,
                                  int* __restrict__ cnt, int* __restrict__ rank,
                                  int nE)
{
  int e = blockIdx.x * blockDim.x + threadIdx.x;
  if (e < nE) rank[e] = atomicAdd(&cnt[ei[nE + e]], 1);
}

__global__ void scan1(const int* __restrict__ cnt, int* __restrict__ excl,
                      int* __restrict__ blockSums, int n)
{
  __shared__ int s[256];
  int i = blockIdx.x * 256 + threadIdx.x;
  int v = (i < n) ? cnt[i] : 0;
  s[threadIdx.x] = v;
  __syncthreads();
  for (int ofs = 1; ofs < 256; ofs <<= 1) {
    int t = (threadIdx.x >= ofs) ? s[threadIdx.x - ofs] : 0;
    __syncthreads();
    s[threadIdx.x] += t;
    __syncthreads();
  }
  if (i < n) excl[i] = s[threadIdx.x] - v;
  if (threadIdx.x == 255) blockSums[blockIdx.x] = s[255];
}

__global__ void scan2(int* __restrict__ blockSums, int nb)
{
  __shared__ int s[1024];
  int tid = threadIdx.x;
  int v = (tid < nb) ? blockSums[tid] : 0;
  s[tid] = v;
  __syncthreads();
  for (int ofs = 1; ofs < 1024; ofs <<= 1) {
    int t = (tid >= ofs) ? s[tid - ofs] : 0;
    __syncthreads();
    s[tid] += t;
    __syncthreads();
  }
  if (tid < nb) blockSums[tid] = s[tid] - v;   // exclusive
}

__global__ void scan3(const int* __restrict__ excl,
                      const int* __restrict__ blockSums,
                      int* __restrict__ rowptr, int n, int nE)
{
  int i = blockIdx.x * blockDim.x + threadIdx.x;
  if (i < n) rowptr[i] = excl[i] + blockSums[i >> 8];
  if (i == n) rowptr[n] = nE;
}

__global__ void scatter2_kernel(const int* __restrict__ ei,
                                const int* __restrict__ rowptr,
                                const int* __restrict__ rank,
                                int* __restrict__ adj, int nE)
{
  int e = blockIdx.x * blockDim.x + threadIdx.x;
  if (e >= nE) return;
  int dst = ei[nE + e];
  adj[rowptr[dst] + rank[e]] = ei[e];
}

// ------- gather + fused BN stats: grid-stride, one wave per node -----------
__global__ __launch_bounds__(256) void gat_gather_stats(
    const int* __restrict__ rowptr, const int* __restrict__ adj,
    const uint32* __restrict__ xwb,
    const float* __restrict__ ALs, const float* __restrict__ ALd,
    const float* __restrict__ bias,
    float* __restrict__ y, float* __restrict__ stats, int nN)
{
  __shared__ float sst[256];
  sst[threadIdx.x] = 0.f;
  __syncthreads();

  const int lane = threadIdx.x & 63;
  const int wly  = threadIdx.x >> 6;       // wave index in block
  const int h    = lane >> 4;              // head of features 2*lane, 2*lane+1
  const int f0   = lane * 2;
  const float b0 = bias[f0], b1 = bias[f0 + 1];
  const int nw   = gridDim.x * 4;          // total waves in grid

  float s1a = 0.f, s1b = 0.f, s2a = 0.f, s2b = 0.f;

  for (int nd = blockIdx.x * 4 + wly; nd < nN; nd += nw) {
    int node = __builtin_amdgcn_readfirstlane(nd);
    float ad = ALd[node * NH + h];

    float acc0, acc1, den;
    {  // self loop
      float e = ALs[node * NH + h] + ad;
      e = (e >= 0.f) ? e : SLOPE * e;
      float w = __expf(e);
      uint32 u = xwb[(size_t)node * 64 + lane];
      acc0 = w * bf_lo(u); acc1 = w * bf_hi(u); den = w;
    }

    int beg = rowptr[node];
    int end = rowptr[node + 1];
    int p = beg;
    for (; p + 1 < end; p += 2) {       // 2 independent row loads in flight
      int s0 = adj[p], s1 = adj[p + 1];
      uint32 u0 = xwb[(size_t)s0 * 64 + lane];
      uint32 u1 = xwb[(size_t)s1 * 64 + lane];
      float e0 = ALs[s0 * NH + h] + ad; e0 = (e0 >= 0.f) ? e0 : SLOPE * e0;
      float e1 = ALs[s1 * NH + h] + ad; e1 = (e1 >= 0.f) ? e1 : SLOPE * e1;
      float w0 = __expf(e0), w1 = __expf(e1);
      acc0 = fmaf(w0, bf_lo(u0), acc0); acc1 = fmaf(w0, bf_hi(u0), acc1); den += w0;
      acc0 = fmaf(w1, bf_lo(u1), acc0); acc1 = fmaf(w1, bf_hi(u1), acc1); den += w1;
    }
    if (p < end) {
      int s0 = adj[p];
      uint32 u0 = xwb[(size_t)s0 * 64 + lane];
      float e0 = ALs[s0 * NH + h] + ad; e0 = (e0 >= 0.f) ? e0 : SLOPE * e0;
      float w0 = __expf(e0);
      acc0 = fmaf(w0, bf_lo(u0), acc0); acc1 = fmaf(w0, bf_hi(u0), acc1); den += w0;
    }

    float inv = 1.f / den;
    float ox = acc0 * inv + b0;
    float oy = acc1 * inv + b1;
    *(float2*)&y[(size_t)node * NF + f0] = make_float2(ox, oy);
    s1a += ox; s1b += oy;
    s2a += ox * ox; s2b += oy * oy;
  }

  // block-level stats reduce: sst[0..127]=sum, sst[128..255]=sumsq
  atomicAdd(&sst[f0], s1a);       atomicAdd(&sst[f0 + 1], s1b);
  atomicAdd(&sst[128 + f0], s2a); atomicAdd(&sst[128 + f0 + 1], s2b);
  __syncthreads();
  atomicAdd(&stats[threadIdx.x], sst[threadIdx.x]);
}

// ---------------- BN + ELU --------------------------------------------------
__global__ void bn_elu(const float* __restrict__ y,
                       const float* __restrict__ stats,
                       const float* __restrict__ gamma,
                       const float* __restrict__ beta,
                       float* __restrict__ out, int nN)
{
  int t = blockIdx.x * blockDim.x + threadIdx.x;
  int total = nN * NF;
  if (t >= total) return;
  int f = t & (NF - 1);
  float inv_n = 1.f / (float)nN;
  float mu = stats[f] * inv_n;
  float var = stats[NF + f] * inv_n - mu * mu;
  float v = (y[t] - mu) * rsqrtf(var + BNEPS) * gamma[f] + beta[f];
  out[t] = (v > 0.f) ? v : expm1f(v);
}

extern "C" void kernel_launch(void* const* d_in, const int* in_sizes, int n_in,
                              void* d_out, int out_size, void* d_ws, size_t ws_size,
                              hipStream_t stream)
{
  const float* x   = (const float*)d_in[0];
  const int*   ei  = (const int*)d_in[1];
  const float* W1  = (const float*)d_in[2];
  const float* a1s = (const float*)d_in[3];
  const float* a1d = (const float*)d_in[4];
  const float* b1  = (const float*)d_in[5];
  const float* g1  = (const float*)d_in[6];
  const float* be1 = (const float*)d_in[7];
  const float* W2  = (const float*)d_in[8];
  const float* a2s = (const float*)d_in[9];
  const float* a2d = (const float*)d_in[10];
  const float* b2  = (const float*)d_in[11];
  const float* g2  = (const float*)d_in[12];
  const float* be2 = (const float*)d_in[13];
  float* out = (float*)d_out;

  const int nN = in_sizes[0] / NF;   // 100000
  const int nE = in_sizes[1] / 2;    // 1600000
  const int nb = (nN + 255) / 256;   // scan blocks (<=1024 required)

  float* ws = (float*)d_ws;
  size_t off = 0;
  uint32* xwb  = (uint32*)(ws + off); off += (size_t)nN * 64;   // bf16 xw, 25.6 MB
  float* ybuf  = ws + off; off += (size_t)nN * NF;
  float* ALs   = ws + off; off += (size_t)nN * NH;
  float* ALd   = ws + off; off += (size_t)nN * NH;
  float* stats = ws + off; off += 256;
  int* ibase   = (int*)(ws + off);
  int* cnt       = ibase;                     // nN
  int* excl      = ibase + nN;                // nN
  int* blockSums = ibase + 2 * nN;            // nb (<1024)
  int* rowptr    = ibase + 2 * nN + 1024;     // nN+1
  int* rank      = rowptr + nN + 2;           // nE
  int* adj       = rank + nE;                 // nE
  float* hbuf  = out;                         // layer-1 activations in d_out

  const int gemm_grid = (nN + 63) / 64;
  const int e_grid    = (nE + 255) / 256;
  const int g_grid    = 2048;                 // grid-stride gather
  const int bn_grid   = (nN * NF + 255) / 256;

  // ---------------- CSR build (once, shared by both layers) ----------------
  hipMemsetAsync(cnt, 0, (size_t)nN * sizeof(int), stream);
  count_rank_kernel<<<e_grid, 256, 0, stream>>>(ei, cnt, rank, nE);
  scan1<<<nb, 256, 0, stream>>>(cnt, excl, blockSums, nN);
  scan2<<<1, 1024, 0, stream>>>(blockSums, nb);
  scan3<<<(nN + 256) / 256, 256, 0, stream>>>(excl, blockSums, rowptr, nN, nE);
  scatter2_kernel<<<e_grid, 256, 0, stream>>>(ei, rowptr, rank, adj, nE);

  // ---------------- layer 1 ----------------
  hipMemsetAsync(stats, 0, 256 * sizeof(float), stream);
  gemm_xw_al<<<gemm_grid, 256, 0, stream>>>(x, W1, a1s, a1d, xwb, ALs, ALd, nN);
  gat_gather_stats<<<g_grid, 256, 0, stream>>>(rowptr, adj, xwb, ALs, ALd, b1,
                                               ybuf, stats, nN);
  bn_elu<<<bn_grid, 256, 0, stream>>>(ybuf, stats, g1, be1, hbuf, nN);

  // ---------------- layer 2 ----------------
  hipMemsetAsync(stats, 0, 256 * sizeof(float), stream);
  gemm_xw_al<<<gemm_grid, 256, 0, stream>>>(hbuf, W2, a2s, a2d, xwb, ALs, ALd, nN);
  gat_gather_stats<<<g_grid, 256, 0, stream>>>(rowptr, adj, xwb, ALs, ALd, b2,
                                               ybuf, stats, nN);
  bn_elu<<<bn_grid, 256, 0, stream>>>(ybuf, stats, g2, be2, out, nN);
}

// Round 14
// 609.166 us; speedup vs baseline: 38.6014x; 1.0425x over previous
//
#include <hip/hip_runtime.h>

#define NF   128
#define NH   4
#define FHD  32
#define BNEPS 1e-5f
#define SLOPE 0.2f

typedef unsigned int uint32;

// bf16 helpers (packed 2×bf16 in a uint32; elem0 = bits[15:0], elem1 = bits[31:16])
__device__ __forceinline__ float bf_lo(uint32 u) { return __uint_as_float(u << 16); }
__device__ __forceinline__ float bf_hi(uint32 u) { return __uint_as_float(u & 0xFFFF0000u); }
__device__ __forceinline__ uint32 bf_rnd(float x) {          // RNE round to bf16
  uint32 u = __float_as_uint(x);
  return (u + 0x7FFFu + ((u >> 16) & 1u)) >> 16;
}
__device__ __forceinline__ uint32 pack2(float a, float b) {
  return bf_rnd(a) | (bf_rnd(b) << 16);
}
__device__ __forceinline__ float elu1(float v) {
  return (v > 0.f) ? v : expm1f(v);
}

// ------- GEMM + fused attention logits (+ optional fused input BN+ELU) -----
// XWB = bf16(BNELU?(X) @ W); ALs/ALd = per-(node,head) logit dots (fp32 acc).
// If bn_stats != nullptr, X is the RAW previous-layer y and BN+ELU is applied
// during LDS staging (scale/shift precomputed from stats; identical fp32 math).
__global__ __launch_bounds__(256) void gemm_xw_al(
    const float* __restrict__ X, const float* __restrict__ W,
    const float* __restrict__ a_src, const float* __restrict__ a_dst,
    const float* __restrict__ bn_stats, const float* __restrict__ gamma,
    const float* __restrict__ beta,
    uint32* __restrict__ XWB, float* __restrict__ ALs, float* __restrict__ ALd,
    int nrows)
{
  __shared__ __align__(16) float sXT[128][68];
  __shared__ __align__(16) float sW[32][128];
  __shared__ float sAs[128], sAd[128];
  __shared__ float sScale[128], sShift[128];
  const int t = threadIdx.x;
  const int row0 = blockIdx.x * 64;

  if (t < 128) sAs[t] = a_src[t];
  else         sAd[t - 128] = a_dst[t - 128];
  const bool do_bn = (bn_stats != nullptr);
  if (do_bn && t < 128) {
    float inv_n = 1.f / (float)nrows;
    float mu  = bn_stats[t] * inv_n;
    float var = bn_stats[128 + t] * inv_n - mu * mu;
    float sc  = gamma[t] * rsqrtf(var + BNEPS);
    sScale[t] = sc;
    sShift[t] = beta[t] - mu * sc;
  }
  __syncthreads();

  for (int i = t; i < 64 * 32; i += 256) {
    int r = i >> 5, c4 = (i & 31) << 2;
    int gr = row0 + r;
    float4 v = make_float4(0.f, 0.f, 0.f, 0.f);
    if (gr < nrows) v = *(const float4*)&X[(size_t)gr * NF + c4];
    if (do_bn) {
      v.x = elu1(v.x * sScale[c4 + 0] + sShift[c4 + 0]);
      v.y = elu1(v.y * sScale[c4 + 1] + sShift[c4 + 1]);
      v.z = elu1(v.z * sScale[c4 + 2] + sShift[c4 + 2]);
      v.w = elu1(v.w * sScale[c4 + 3] + sShift[c4 + 3]);
    }
    sXT[c4 + 0][r] = v.x; sXT[c4 + 1][r] = v.y;
    sXT[c4 + 2][r] = v.z; sXT[c4 + 3][r] = v.w;
  }

  const int tx = t & 15;
  const int ty = t >> 4;
  const int c0 = tx << 3;
  const int r0 = ty << 2;
  float acc[4][8];
  #pragma unroll
  for (int i = 0; i < 4; i++)
    #pragma unroll
    for (int j = 0; j < 8; j++) acc[i][j] = 0.f;

  for (int q = 0; q < 4; ++q) {
    __syncthreads();
    for (int i = t; i < 32 * 32; i += 256) {
      int kk = i >> 5, c4 = (i & 31) << 2;
      *(float4*)&sW[kk][c4] = *(const float4*)&W[(size_t)(q * 32 + kk) * NF + c4];
    }
    __syncthreads();
    #pragma unroll 4
    for (int kk = 0; kk < 32; ++kk) {
      int k = q * 32 + kk;
      float4 xv = *(const float4*)&sXT[k][r0];
      float4 w0 = *(const float4*)&sW[kk][c0];
      float4 w1 = *(const float4*)&sW[kk][c0 + 4];
      float xr[4] = {xv.x, xv.y, xv.z, xv.w};
      float wr[8] = {w0.x, w0.y, w0.z, w0.w, w1.x, w1.y, w1.z, w1.w};
      #pragma unroll
      for (int i = 0; i < 4; i++)
        #pragma unroll
        for (int j = 0; j < 8; j++)
          acc[i][j] = fmaf(xr[i], wr[j], acc[i][j]);
    }
  }

  const int hd  = tx >> 2;          // head of this thread's 8 cols
  const int off = (tx & 3) << 3;    // offset within head
  #pragma unroll
  for (int i = 0; i < 4; i++) {
    int gr = row0 + r0 + i;
    float ps = 0.f, pd = 0.f;
    #pragma unroll
    for (int j = 0; j < 8; j++) {
      ps += acc[i][j] * sAs[hd * FHD + off + j];
      pd += acc[i][j] * sAd[hd * FHD + off + j];
    }
    // quad reduce (threads t, t^1, t^2, t^3 share row-group & head)
    ps += __shfl_xor(ps, 1); ps += __shfl_xor(ps, 2);
    pd += __shfl_xor(pd, 1); pd += __shfl_xor(pd, 2);
    if (gr < nrows) {
      uint4 pk;
      pk.x = pack2(acc[i][0], acc[i][1]);
      pk.y = pack2(acc[i][2], acc[i][3]);
      pk.z = pack2(acc[i][4], acc[i][5]);
      pk.w = pack2(acc[i][6], acc[i][7]);
      *(uint4*)&XWB[(size_t)gr * 64 + (c0 >> 1)] = pk;
      if ((t & 3) == 0) {
        ALs[gr * NH + hd] = ps;
        ALd[gr * NH + hd] = pd;
      }
    }
  }
}

// ---------------- CSR build (rank-based, no atomic in scatter) -------------
__global__ void count_rank_kernel(const int* __restrict__ ei,
                                  int* __restrict__ cnt, int* __restrict__ rank,
                                  int nE)
{
  int e = blockIdx.x * blockDim.x + threadIdx.x;
  if (e < nE) rank[e] = atomicAdd(&cnt[ei[nE + e]], 1);
}

__global__ void scan1(const int* __restrict__ cnt, int* __restrict__ excl,
                      int* __restrict__ blockSums, int n)
{
  __shared__ int s[256];
  int i = blockIdx.x * 256 + threadIdx.x;
  int v = (i < n) ? cnt[i] : 0;
  s[threadIdx.x] = v;
  __syncthreads();
  for (int ofs = 1; ofs < 256; ofs <<= 1) {
    int t = (threadIdx.x >= ofs) ? s[threadIdx.x - ofs] : 0;
    __syncthreads();
    s[threadIdx.x] += t;
    __syncthreads();
  }
  if (i < n) excl[i] = s[threadIdx.x] - v;
  if (threadIdx.x == 255) blockSums[blockIdx.x] = s[255];
}

__global__ void scan2(int* __restrict__ blockSums, int nb)
{
  __shared__ int s[1024];
  int tid = threadIdx.x;
  int v = (tid < nb) ? blockSums[tid] : 0;
  s[tid] = v;
  __syncthreads();
  for (int ofs = 1; ofs < 1024; ofs <<= 1) {
    int t = (tid >= ofs) ? s[tid - ofs] : 0;
    __syncthreads();
    s[tid] += t;
    __syncthreads();
  }
  if (tid < nb) blockSums[tid] = s[tid] - v;   // exclusive
}

// also zeroes the 512-float stats region (stats1+stats2)
__global__ void scan3(const int* __restrict__ excl,
                      const int* __restrict__ blockSums,
                      int* __restrict__ rowptr, float* __restrict__ statsz,
                      int n, int nE)
{
  int i = blockIdx.x * blockDim.x + threadIdx.x;
  if (i < n) rowptr[i] = excl[i] + blockSums[i >> 8];
  if (i == n) rowptr[n] = nE;
  if (i < 512) statsz[i] = 0.f;
}

__global__ void scatter2_kernel(const int* __restrict__ ei,
                                const int* __restrict__ rowptr,
                                const int* __restrict__ rank,
                                int* __restrict__ adj, int nE)
{
  int e = blockIdx.x * blockDim.x + threadIdx.x;
  if (e >= nE) return;
  int dst = ei[nE + e];
  adj[rowptr[dst] + rank[e]] = ei[e];
}

// ------- gather + fused BN stats: grid-stride, one wave per node, 4-deep ---
__global__ __launch_bounds__(256) void gat_gather_stats(
    const int* __restrict__ rowptr, const int* __restrict__ adj,
    const uint32* __restrict__ xwb,
    const float* __restrict__ ALs, const float* __restrict__ ALd,
    const float* __restrict__ bias,
    float* __restrict__ y, float* __restrict__ stats, int nN)
{
  __shared__ float sst[256];
  sst[threadIdx.x] = 0.f;
  __syncthreads();

  const int lane = threadIdx.x & 63;
  const int wly  = threadIdx.x >> 6;       // wave index in block
  const int h    = lane >> 4;              // head of features 2*lane, 2*lane+1
  const int f0   = lane * 2;
  const float b0 = bias[f0], b1 = bias[f0 + 1];
  const int nw   = gridDim.x * 4;          // total waves in grid

  float s1a = 0.f, s1b = 0.f, s2a = 0.f, s2b = 0.f;

  for (int nd = blockIdx.x * 4 + wly; nd < nN; nd += nw) {
    int node = __builtin_amdgcn_readfirstlane(nd);
    float ad = ALd[node * NH + h];

    float acc0, acc1, den;
    {  // self loop
      float e = ALs[node * NH + h] + ad;
      e = (e >= 0.f) ? e : SLOPE * e;
      float w = __expf(e);
      uint32 u = xwb[(size_t)node * 64 + lane];
      acc0 = w * bf_lo(u); acc1 = w * bf_hi(u); den = w;
    }

    int beg = rowptr[node];
    int end = rowptr[node + 1];
    int p = beg;
    for (; p + 3 < end; p += 4) {       // 4 independent row loads in flight
      int s0 = adj[p], s1 = adj[p + 1], s2 = adj[p + 2], s3 = adj[p + 3];
      uint32 u0 = xwb[(size_t)s0 * 64 + lane];
      uint32 u1 = xwb[(size_t)s1 * 64 + lane];
      uint32 u2 = xwb[(size_t)s2 * 64 + lane];
      uint32 u3 = xwb[(size_t)s3 * 64 + lane];
      float e0 = ALs[s0 * NH + h] + ad; e0 = (e0 >= 0.f) ? e0 : SLOPE * e0;
      float e1 = ALs[s1 * NH + h] + ad; e1 = (e1 >= 0.f) ? e1 : SLOPE * e1;
      float e2 = ALs[s2 * NH + h] + ad; e2 = (e2 >= 0.f) ? e2 : SLOPE * e2;
      float e3 = ALs[s3 * NH + h] + ad; e3 = (e3 >= 0.f) ? e3 : SLOPE * e3;
      float w0 = __expf(e0), w1 = __expf(e1), w2 = __expf(e2), w3 = __expf(e3);
      acc0 = fmaf(w0, bf_lo(u0), acc0); acc1 = fmaf(w0, bf_hi(u0), acc1); den += w0;
      acc0 = fmaf(w1, bf_lo(u1), acc0); acc1 = fmaf(w1, bf_hi(u1), acc1); den += w1;
      acc0 = fmaf(w2, bf_lo(u2), acc0); acc1 = fmaf(w2, bf_hi(u2), acc1); den += w2;
      acc0 = fmaf(w3, bf_lo(u3), acc0); acc1 = fmaf(w3, bf_hi(u3), acc1); den += w3;
    }
    for (; p < end; ++p) {
      int s0 = adj[p];
      uint32 u0 = xwb[(size_t)s0 * 64 + lane];
      float e0 = ALs[s0 * NH + h] + ad; e0 = (e0 >= 0.f) ? e0 : SLOPE * e0;
      float w0 = __expf(e0);
      acc0 = fmaf(w0, bf_lo(u0), acc0); acc1 = fmaf(w0, bf_hi(u0), acc1); den += w0;
    }

    float inv = 1.f / den;
    float ox = acc0 * inv + b0;
    float oy = acc1 * inv + b1;
    *(float2*)&y[(size_t)node * NF + f0] = make_float2(ox, oy);
    s1a += ox; s1b += oy;
    s2a += ox * ox; s2b += oy * oy;
  }

  // block-level stats reduce: sst[0..127]=sum, sst[128..255]=sumsq
  atomicAdd(&sst[f0], s1a);       atomicAdd(&sst[f0 + 1], s1b);
  atomicAdd(&sst[128 + f0], s2a); atomicAdd(&sst[128 + f0 + 1], s2b);
  __syncthreads();
  atomicAdd(&stats[threadIdx.x], sst[threadIdx.x]);
}

// ---------------- BN + ELU (final output only) ------------------------------
__global__ void bn_elu(const float* __restrict__ y,
                       const float* __restrict__ stats,
                       const float* __restrict__ gamma,
                       const float* __restrict__ beta,
                       float* __restrict__ out, int nN)
{
  int t = blockIdx.x * blockDim.x + threadIdx.x;
  int total = nN * NF;
  if (t >= total) return;
  int f = t & (NF - 1);
  float inv_n = 1.f / (float)nN;
  float mu = stats[f] * inv_n;
  float var = stats[NF + f] * inv_n - mu * mu;
  float v = (y[t] - mu) * rsqrtf(var + BNEPS) * gamma[f] + beta[f];
  out[t] = (v > 0.f) ? v : expm1f(v);
}

extern "C" void kernel_launch(void* const* d_in, const int* in_sizes, int n_in,
                              void* d_out, int out_size, void* d_ws, size_t ws_size,
                              hipStream_t stream)
{
  const float* x   = (const float*)d_in[0];
  const int*   ei  = (const int*)d_in[1];
  const float* W1  = (const float*)d_in[2];
  const float* a1s = (const float*)d_in[3];
  const float* a1d = (const float*)d_in[4];
  const float* b1  = (const float*)d_in[5];
  const float* g1  = (const float*)d_in[6];
  const float* be1 = (const float*)d_in[7];
  const float* W2  = (const float*)d_in[8];
  const float* a2s = (const float*)d_in[9];
  const float* a2d = (const float*)d_in[10];
  const float* b2  = (const float*)d_in[11];
  const float* g2  = (const float*)d_in[12];
  const float* be2 = (const float*)d_in[13];
  float* out = (float*)d_out;

  const int nN = in_sizes[0] / NF;   // 100000
  const int nE = in_sizes[1] / 2;    // 1600000
  const int nb = (nN + 255) / 256;   // scan blocks (<=1024 required)

  float* ws = (float*)d_ws;
  size_t off = 0;
  uint32* xwb  = (uint32*)(ws + off); off += (size_t)nN * 64;   // bf16 xw, 25.6 MB
  float* ybuf  = ws + off; off += (size_t)nN * NF;
  float* ALs   = ws + off; off += (size_t)nN * NH;
  float* ALd   = ws + off; off += (size_t)nN * NH;
  float* stats = ws + off; off += 512;        // stats1 | stats2
  float* stats1 = stats;
  float* stats2 = stats + 256;
  int* ibase   = (int*)(ws + off);
  int* cnt       = ibase;                     // nN
  int* excl      = ibase + nN;                // nN
  int* blockSums = ibase + 2 * nN;            // nb (<1024)
  int* rowptr    = ibase + 2 * nN + 1024;     // nN+1
  int* rank      = rowptr + nN + 2;           // nE
  int* adj       = rank + nE;                 // nE

  const int gemm_grid = (nN + 63) / 64;
  const int e_grid    = (nE + 255) / 256;
  const int g_grid    = 2048;                 // grid-stride gather
  const int bn_grid   = (nN * NF + 255) / 256;

  // ---------------- CSR build (once, shared by both layers) ----------------
  hipMemsetAsync(cnt, 0, (size_t)nN * sizeof(int), stream);
  count_rank_kernel<<<e_grid, 256, 0, stream>>>(ei, cnt, rank, nE);
  scan1<<<nb, 256, 0, stream>>>(cnt, excl, blockSums, nN);
  scan2<<<1, 1024, 0, stream>>>(blockSums, nb);
  scan3<<<(nN + 256) / 256, 256, 0, stream>>>(excl, blockSums, rowptr, stats, nN, nE);
  scatter2_kernel<<<e_grid, 256, 0, stream>>>(ei, rowptr, rank, adj, nE);

  // ---------------- layer 1 ----------------
  gemm_xw_al<<<gemm_grid, 256, 0, stream>>>(x, W1, a1s, a1d,
                                            nullptr, nullptr, nullptr,
                                            xwb, ALs, ALd, nN);
  gat_gather_stats<<<g_grid, 256, 0, stream>>>(rowptr, adj, xwb, ALs, ALd, b1,
                                               ybuf, stats1, nN);

  // ---------------- layer 2 (BN+ELU of layer-1 fused into GEMM X-load) ----
  gemm_xw_al<<<gemm_grid, 256, 0, stream>>>(ybuf, W2, a2s, a2d,
                                            stats1, g1, be1,
                                            xwb, ALs, ALd, nN);
  gat_gather_stats<<<g_grid, 256, 0, stream>>>(rowptr, adj, xwb, ALs, ALd, b2,
                                               ybuf, stats2, nN);
  bn_elu<<<bn_grid, 256, 0, stream>>>(ybuf, stats2, g2, be2, out, nN);
}